// Round 1
// baseline (648.812 us; speedup 1.0000x reference)
//
#include <hip/hip_runtime.h>

#define TLEN  4096
#define NROWS 4096
#define WPB   8                  // waves per block -> 2 waves per SIMD (the point of this round)
#define RPW   32                 // rows per wave (fast-path logic unchanged at this granularity)
#define RPB   (WPB * RPW)        // 256 rows per block
#define K     16                 // timesteps per chunk (32 -> 16 so 8 waves' LDS fits in 160 KB)
#define NC    (TLEN / K)         // 256 chunks
#define LDPAD 34                 // staged-output row pitch (dwords): 32 data + 2 pad (keeps 8B align)
#define IBW   (2 * (K / 2) * 32) // per-wave ibuf float4s: 2 bufs x 8 tp x 32 rows = 512 (8 KB)
#define UN    8                  // exact-path unroll

__device__ __forceinline__ float fexp2(float x) { return __builtin_amdgcn_exp2f(x); }
__device__ __forceinline__ float frcp(float x)  { return __builtin_amdgcn_rcpf(x); }
__device__ __forceinline__ float sigz(float z)  { return frcp(1.0f + fexp2(z)); }

// Swap adjacent lanes (lane ^ 1): DPP quad_perm [1,0,3,2].
__device__ __forceinline__ float lane_swap1(float v) {
    int r = __builtin_amdgcn_update_dpp(0, __float_as_int(v), 0xB1, 0xF, 0xF, true);
    return __int_as_float(r);
}

// Async global->LDS DMA, 16 B per lane. LDS dest = uniform base + lane*16.
__device__ __forceinline__ void gload_lds16(const float4* g, float4* l) {
    __builtin_amdgcn_global_load_lds((const __attribute__((address_space(1))) void*)g,
                                     (__attribute__((address_space(3))) void*)l,
                                     16, 0, 0);
}
// Wait all outstanding VMEM of THIS wave (counters are per-wave; waves stay decoupled),
// and pin ordering so following ds_reads can't be hoisted above it.
__device__ __forceinline__ void fence_vm0() {
    __builtin_amdgcn_s_waitcnt(0x0f70);   // vmcnt(0); lgkmcnt/expcnt unconstrained
    __builtin_amdgcn_sched_barrier(0);
}

// ---------------------------------------------------------------------------
// Fast path, per-wave (identical math to the verified 384us kernel; only the
// chunk length and LDS slicing changed). Lane pair (2r, 2r+1) owns row r:
// even lane = x, odd = y. Carried state: s (own state), sig = sigmoid(std*(s-mean)),
// advanced by deg-2 Taylor in dz (|dz| <= 0.05 guarded), exact-resynced每 chunk
// (now every 16 steps instead of 32 -> strictly less drift).
// 8 such waves run per block with NO inter-wave coupling: each has its own
// 32 rows, own ibuf/st LDS slice, own DMA kicks, own vmcnt. Two waves land on
// each SIMD and fill each other's dependency/issue stalls.
// ---------------------------------------------------------------------------
__device__ void run_fast(const float* __restrict__ inp, const float* __restrict__ prm,
                         float* __restrict__ out,
                         float4* __restrict__ ibuf,   // per-wave [2][K/2 tp][32 row] float4
                         float* __restrict__ st) {    // per-wave [RPW][LDPAD]
    const int lane = threadIdx.x & 63;
    const int wave = threadIdx.x >> 6;
    const int R0   = blockIdx.x * RPB + wave * RPW;
    const int r_   = lane >> 1;
    const int par  = lane & 1;

    const float L2E = 1.4426950408889634f;
    const int inB = par ? 6 : 2, sfB = par ? 22 : 18, t2B = par ? 10 : 14;
    const float ic  = 1.0f / prm[par];
    const float g1  = prm[sfB] * ic, P1 = g1 * prm[sfB + 3], Gn1 = -g1; // self dir
    const float g2  = prm[t2B] * ic, P2 = g2 * prm[t2B + 3], Gn2 = -g2; // cross dir
    const float gA  = prm[inB] * ic, PA = gA * prm[inB + 3], GnA = -gA; // input dir
    const float c1i = -prm[inB + 2] * L2E, c0i = prm[inB + 2] * prm[inB + 1] * L2E;
    const float sdz = prm[sfB + 2];                       // natural-arg scale
    const float c1s = -sdz * L2E, c0s = sdz * prm[sfB + 1] * L2E;

    float x   = par ? 1.0f : 0.0f;
    float sig = sigz(__builtin_fmaf(c1s, x, c0s));
    float u   = __builtin_fmaf(-sig, sig, sig);           // sig*(1-sig)
    float q   = 0.5f - sig;

    float2* __restrict__ out2 = (float2*)out;
    float*  wp = st + r_ * LDPAD + par;

    // global source: per-lane row = lane&31, half = lane>>5
    const float4* gbase = (const float4*)inp
                        + (size_t)(R0 + (lane & 31)) * (TLEN / 2) + (lane >> 5);
    auto kick = [&](int c) {   // stage chunk c into ibuf[c&1]; layout idx = tp*32+row
        float4* lb = ibuf + ((c & 1) * (IBW / 2));
        const float4* gp = gbase + c * (K / 2);
#pragma unroll
        for (int j = 0; j < K / 4; ++j)                   // 4 DMA ops per 16-step chunk
            gload_lds16(gp + 2 * j, lb + (j << 6));       // LDS[j*64+lane] <- g
    };

    auto step = [&](float va, int t) {
        float sgin = sigz(__builtin_fmaf(c1i, va, c0i));  // off-chain (va known early)
        float Av  = __builtin_fmaf(GnA, x, PA);
        float t1v = __builtin_fmaf(Gn1, x, P1);
        float t2v = __builtin_fmaf(Gn2, x, P2);
        float m   = sgin * Av;
        float b2  = __builtin_fmaf(sig, t1v, m);
        float sc  = lane_swap1(sig);                      // partner's sigma
        float dx  = __builtin_fmaf(sc, t2v, b2);
        x = x + dx;
        wp[2 * t] = x;                                    // ds_write_b32, imm offset
        float dz  = sdz * dx;
        float tt  = __builtin_fmaf(q, dz, 1.0f);
        float aa  = dz * tt;
        sig = __builtin_fmaf(u, aa, sig);                 // deg-2 Taylor step
        u   = __builtin_fmaf(-sig, sig, sig);
        q   = 0.5f - sig;
    };

    kick(0);
    fence_vm0();
    float4 f0 = ibuf[0 * 32 + r_];
    float4 f1 = ibuf[1 * 32 + r_];
    kick(1);

    for (int c = 0; c < NC; ++c) {
        float4* lb = ibuf + ((c & 1) * (IBW / 2));
#pragma unroll
        for (int tp = 0; tp < K / 2; ++tp) {
            float4 f = f0; f0 = f1;
            if (tp < K / 2 - 2) f1 = lb[(tp + 2) * 32 + r_];  // 2-pair lookahead
            step(par ? f.y : f.x, 2 * tp);
            step(par ? f.w : f.z, 2 * tp + 1);
        }
        // exact re-sync: kills Taylor drift (off the per-step chain)
        sig = sigz(__builtin_fmaf(c1s, x, c0s));
        u   = __builtin_fmaf(-sig, sig, sig);
        q   = 0.5f - sig;

        if (c + 1 < NC) {
            fence_vm0();                                  // chunk c+1 DMA complete
            float4* ln = ibuf + (((c + 1) & 1) * (IBW / 2));
            f0 = ln[0 * 32 + r_];
            f1 = ln[1 * 32 + r_];
        }
        // flush chunk c: 32 rows x 16 steps x (x,y), coalesced 128 B runs
#pragma unroll
        for (int j = 0; j < 8; ++j) {
            int ro  = 4 * j + (lane >> 4);
            int col = lane & 15;
            float2 v = *(const float2*)&st[ro * LDPAD + col * 2];
            out2[(size_t)(R0 + ro) * TLEN + (size_t)c * K + col] = v;
        }
        if (c + 2 < NC) kick(c + 2);                      // reuse just-consumed buffer
    }
}

// ---------------------------------------------------------------------------
// Exact fallback (round-1 proven path) for general params.
// ---------------------------------------------------------------------------
struct LaneConst {
    float c1_in, c0_in, c1_sf, c0_sf, c1_ot, c0_ot;
    float gS_in, gS_cr, gS_sf, gP_in, gP_cr, gP_sf;
};

template<bool SHARED>
__device__ __forceinline__ float do_step_exact(float s, float pre_in, const LaneConst& k) {
    float sig_in = sigz(__builtin_fmaf(k.c1_in, pre_in, k.c0_in));
    float sig_sf = sigz(__builtin_fmaf(k.c1_sf, s, k.c0_sf));
    float sig_ot;
    if (SHARED) sig_ot = sig_sf;
    else        sig_ot = sigz(__builtin_fmaf(k.c1_ot, s, k.c0_ot));
    float sig_cr = lane_swap1(sig_ot);
    float S = __builtin_fmaf(k.gS_in, sig_in, __builtin_fmaf(k.gS_cr, sig_cr, k.gS_sf * sig_sf));
    float P = __builtin_fmaf(k.gP_in, sig_in, __builtin_fmaf(k.gP_cr, sig_cr, k.gP_sf * sig_sf));
    return s + __builtin_fmaf(S, -s, P);
}

template<bool SHARED>
__device__ void run_exact(const float* __restrict__ inp, const float* __restrict__ prm,
                          float* __restrict__ out) {
    const int tid = blockIdx.x * (64 * WPB) + threadIdx.x;
    const int row = tid >> 1;
    const int par = tid & 1;
    const float L2E = 1.4426950408889634f;
    const int inB = par ? 6 : 2, sfB = par ? 22 : 18, otB = par ? 14 : 10, crB = par ? 10 : 14;
    const float invc = 1.0f / prm[par];
    LaneConst k;
    float sd = prm[inB + 2], mn = prm[inB + 1];
    k.c1_in = -sd * L2E; k.c0_in = sd * mn * L2E;
    sd = prm[sfB + 2]; mn = prm[sfB + 1];
    k.c1_sf = -sd * L2E; k.c0_sf = sd * mn * L2E;
    sd = prm[otB + 2]; mn = prm[otB + 1];
    k.c1_ot = -sd * L2E; k.c0_ot = sd * mn * L2E;
    k.gS_in = prm[inB] * invc; k.gP_in = k.gS_in * prm[inB + 3];
    k.gS_sf = prm[sfB] * invc; k.gP_sf = k.gS_sf * prm[sfB + 3];
    k.gS_cr = prm[crB] * invc; k.gP_cr = k.gS_cr * prm[crB + 3];

    const float4* __restrict__ src = (const float4*)inp + (size_t)row * (TLEN / 2);
    float* __restrict__ dst = out + (size_t)row * (TLEN * 2) + par;
    float s = par ? 1.0f : 0.0f;

    float4 cur[UN], nxt[UN];
#pragma unroll
    for (int j = 0; j < UN; ++j) cur[j] = src[j];
    const int NIT = TLEN / (2 * UN);
    for (int it = 0; it < NIT; ++it) {
        if (it + 1 < NIT) {
#pragma unroll
            for (int j = 0; j < UN; ++j) nxt[j] = src[(it + 1) * UN + j];
        }
        float* dptr = dst + it * (UN * 4);
#pragma unroll
        for (int j = 0; j < UN; ++j) {
            float4 f = cur[j];
            s = do_step_exact<SHARED>(s, par ? f.y : f.x, k);
            dptr[j * 4] = s;
            s = do_step_exact<SHARED>(s, par ? f.w : f.z, k);
            dptr[j * 4 + 2] = s;
        }
#pragma unroll
        for (int j = 0; j < UN; ++j) cur[j] = nxt[j];
    }
}

__global__ __launch_bounds__(64 * WPB, 2)
void memcell_scan(const float* __restrict__ inp, const float* __restrict__ prm,
                  float* __restrict__ out) {
    __shared__ float4 ibuf[WPB * IBW];            // 64 KB: 8 waves x 8 KB DMA double-buffer
    __shared__ float  st[WPB * RPW * LDPAD];      // 34 KB: 8 waves x output staging

    // Device-uniform guard for the fast path (unchanged from the verified kernel):
    //  - shared (mean,std) between self & cross state dirs (xx==xy, yy==yx)
    //  - g >= 0, caps > 0       -> states stay in hull{s0, pots}
    //  - sum(g/cap) <= 0.25     -> no overshoot
    //  - |dz| = std*|ds| <= 0.05 -> deg-2 sigma-Taylor (+ per-chunk exact resync)
    //  - |z| <= 20              -> sigz well-conditioned
    const bool shared = (prm[11] == prm[19]) && (prm[12] == prm[20]) &&
                        (prm[15] == prm[23]) && (prm[16] == prm[24]);
    const float capx = prm[0], capy = prm[1];
    const bool gpos = prm[2] >= 0.f && prm[6] >= 0.f && prm[10] >= 0.f &&
                      prm[14] >= 0.f && prm[18] >= 0.f && prm[22] >= 0.f &&
                      capx > 0.f && capy > 0.f;
    const float sx = (prm[2] + prm[14] + prm[18]) / capx;
    const float sy = (prm[6] + prm[10] + prm[22]) / capy;
    const float lox = fminf(0.f, fminf(prm[5], fminf(prm[17], prm[21])));
    const float hix = fmaxf(0.f, fmaxf(prm[5], fmaxf(prm[17], prm[21])));
    const float loy = fminf(1.f, fminf(prm[9], fminf(prm[13], prm[25])));
    const float hiy = fmaxf(1.f, fmaxf(prm[9], fmaxf(prm[13], prm[25])));
    const float wbx = prm[20] * sx * (hix - lox), wby = prm[24] * sy * (hiy - loy);
    const float zmx = prm[20] * fmaxf(fabsf(lox - prm[19]), fabsf(hix - prm[19]));
    const float zmy = prm[24] * fmaxf(fabsf(loy - prm[23]), fabsf(hiy - prm[23]));
    const bool fast = shared && gpos && sx <= 0.25f && sy <= 0.25f &&
                      wbx <= 0.05f && wby <= 0.05f && zmx <= 20.f && zmy <= 20.f;
    if (fast) {
        const int wave = threadIdx.x >> 6;
        run_fast(inp, prm, out,
                 ibuf + wave * IBW,
                 st   + wave * (RPW * LDPAD));
    } else {
        if (shared) run_exact<true >(inp, prm, out);
        else        run_exact<false>(inp, prm, out);
    }
}

extern "C" void kernel_launch(void* const* d_in, const int* in_sizes, int n_in,
                              void* d_out, int out_size, void* d_ws, size_t ws_size,
                              hipStream_t stream) {
    (void)in_sizes; (void)n_in; (void)d_ws; (void)ws_size; (void)out_size;
    const float* inp = (const float*)d_in[0];
    const float* prm = (const float*)d_in[1];
    float* out = (float*)d_out;
    memcell_scan<<<dim3(NROWS / RPB), dim3(64 * WPB), 0, stream>>>(inp, prm, out);
}

// Round 2
// 570.732 us; speedup vs baseline: 1.1368x; 1.1368x over previous
//
#include <hip/hip_runtime.h>

#define TLEN  4096
#define NROWS 4096
#define RPW   64            // rows per wave: ONE row per lane (x & y fused in-lane)
#define K     16            // timesteps per chunk
#define NC    (TLEN / K)
#define STP   34            // staging pitch (dwords): 32 data (16 steps x {x,y}) + 2 pad
#define UN    8             // exact-path unroll

__device__ __forceinline__ float fexp2(float x) { return __builtin_amdgcn_exp2f(x); }
__device__ __forceinline__ float frcp(float x)  { return __builtin_amdgcn_rcpf(x); }
__device__ __forceinline__ float sigz(float z)  { return frcp(1.0f + fexp2(z)); }

// Swap adjacent lanes (lane ^ 1): DPP quad_perm [1,0,3,2]. (exact path only)
__device__ __forceinline__ float lane_swap1(float v) {
    int r = __builtin_amdgcn_update_dpp(0, __float_as_int(v), 0xB1, 0xF, 0xF, true);
    return __int_as_float(r);
}

// Async global->LDS DMA, 16 B per lane. LDS dest = uniform base + lane*16.
__device__ __forceinline__ void gload_lds16(const float4* g, float4* l) {
    __builtin_amdgcn_global_load_lds((const __attribute__((address_space(1))) void*)g,
                                     (__attribute__((address_space(3))) void*)l,
                                     16, 0, 0);
}
// Wait all outstanding VMEM (this wave's chunk DMA, kicked ~1 chunk earlier),
// and pin ordering so following ds_reads can't be hoisted above it.
__device__ __forceinline__ void fence_vm0() {
    __builtin_amdgcn_s_waitcnt(0x0f70);   // vmcnt(0); lgkmcnt/expcnt unconstrained
    __builtin_amdgcn_sched_barrier(0);
}

// ---------------------------------------------------------------------------
// Fast path, round 2: one lane owns a full row -> both states x,y in-register.
//  - cross-coupling sigma is a plain register (DPP eliminated)
//  - two independent ~24-cyc dependency chains per lane interleave, filling
//    the FMA-latency stalls a single chain leaves on a lone wave
//  - per-state math sequence is BIT-IDENTICAL to the verified round-0 kernel
//    (deg-2 sigma-Taylor, |dz|<=0.05 guarded, exact resync every K steps)
//  - resources per CU identical to the proven round-0 profile: 1 wave, 25 KB
//    LDS, same scattered-row DMA pattern (now 64 rows/op vs 32)
// Blocks 0..63 each run 64 rows; blocks 64..127 exit (grid kept at 128 for
// the exact fallback which needs 8192 lanes).
// ---------------------------------------------------------------------------
__device__ void run_fast(const float* __restrict__ inp, const float* __restrict__ prm,
                         float* __restrict__ out,
                         float4* __restrict__ ibuf,   // [2][K/2 granules][64 lanes] float4
                         float* __restrict__ st) {    // [RPW][STP]
    const int lane = threadIdx.x;
    const int R0   = blockIdx.x * RPW;

    const float L2E = 1.4426950408889634f;
    // x-state: input 'ax'(base 2), self 'xx'(18), cross 'yx'(14), cap prm[0]
    const float icx = 1.0f / prm[0];
    const float g1x = prm[18] * icx, P1x = g1x * prm[21], Gn1x = -g1x;
    const float g2x = prm[14] * icx, P2x = g2x * prm[17], Gn2x = -g2x;
    const float gAx = prm[2]  * icx, PAx = gAx * prm[5],  GnAx = -gAx;
    const float c1ix = -prm[4] * L2E, c0ix = prm[4] * prm[3] * L2E;
    const float sdzx = prm[20];
    const float c1sx = -sdzx * L2E, c0sx = sdzx * prm[19] * L2E;
    // y-state: input 'by'(6), self 'yy'(22), cross 'xy'(10), cap prm[1]
    const float icy = 1.0f / prm[1];
    const float g1y = prm[22] * icy, P1y = g1y * prm[25], Gn1y = -g1y;
    const float g2y = prm[10] * icy, P2y = g2y * prm[13], Gn2y = -g2y;
    const float gAy = prm[6]  * icy, PAy = gAy * prm[9],  GnAy = -gAy;
    const float c1iy = -prm[8] * L2E, c0iy = prm[8] * prm[7] * L2E;
    const float sdzy = prm[24];
    const float c1sy = -sdzy * L2E, c0sy = sdzy * prm[23] * L2E;

    float x = 0.0f, y = 1.0f;
    float sgX = sigz(__builtin_fmaf(c1sx, x, c0sx));
    float sgY = sigz(__builtin_fmaf(c1sy, y, c0sy));
    float uX  = __builtin_fmaf(-sgX, sgX, sgX), qX = 0.5f - sgX;
    float uY  = __builtin_fmaf(-sgY, sgY, sgY), qY = 0.5f - sgY;

    float2* __restrict__ out2 = (float2*)out;
    float*  wp = st + lane * STP;

    // lane's own row, float4 granule = 2 timesteps of (a,b)
    const float4* gbase = (const float4*)inp + (size_t)(R0 + lane) * (TLEN / 2);
    auto kick = [&](int c) {   // stage chunk c into ibuf[c&1]; layout [granule][lane]
        float4* lb = ibuf + ((c & 1) << 9);
        const float4* gp = gbase + c * (K / 2);
#pragma unroll
        for (int j = 0; j < K / 2; ++j)                 // 8 DMA ops per 16-step chunk
            gload_lds16(gp + j, lb + (j << 6));         // LDS[j*64+lane] <- own row
    };

    auto step2 = [&](float a, float b, int t) {
        float sA  = sigz(__builtin_fmaf(c1ix, a, c0ix));   // off-chain (a,b known early)
        float sB  = sigz(__builtin_fmaf(c1iy, b, c0iy));
        float AvX = __builtin_fmaf(GnAx, x, PAx);
        float t1X = __builtin_fmaf(Gn1x, x, P1x);
        float t2X = __builtin_fmaf(Gn2x, x, P2x);
        float AvY = __builtin_fmaf(GnAy, y, PAy);
        float t1Y = __builtin_fmaf(Gn1y, y, P1y);
        float t2Y = __builtin_fmaf(Gn2y, y, P2y);
        float mX  = sA * AvX,                mY  = sB * AvY;
        float b2X = __builtin_fmaf(sgX, t1X, mX);
        float b2Y = __builtin_fmaf(sgY, t1Y, mY);
        float dX  = __builtin_fmaf(sgY, t2X, b2X);         // cross sig: a register now
        float dY  = __builtin_fmaf(sgX, t2Y, b2Y);         // (both use PRE-update sigs)
        x = x + dX;
        y = y + dY;
        float2 w; w.x = x; w.y = y;
        *(float2*)&wp[2 * t] = w;                          // ds_write_b64
        float dzX = sdzx * dX,               dzY = sdzy * dY;
        float ttX = __builtin_fmaf(qX, dzX, 1.0f);
        float ttY = __builtin_fmaf(qY, dzY, 1.0f);
        float aaX = dzX * ttX,               aaY = dzY * ttY;
        sgX = __builtin_fmaf(uX, aaX, sgX);                // deg-2 Taylor step
        sgY = __builtin_fmaf(uY, aaY, sgY);
        uX  = __builtin_fmaf(-sgX, sgX, sgX);
        uY  = __builtin_fmaf(-sgY, sgY, sgY);
        qX  = 0.5f - sgX;
        qY  = 0.5f - sgY;
    };

    kick(0);
    fence_vm0();
    float4 f0 = ibuf[lane];
    float4 f1 = ibuf[64 + lane];
    kick(1);

    for (int c = 0; c < NC; ++c) {
        float4* lb = ibuf + ((c & 1) << 9);
#pragma unroll
        for (int tp = 0; tp < K / 2; ++tp) {
            float4 f = f0; f0 = f1;
            if (tp < K / 2 - 2) f1 = lb[(tp + 2) * 64 + lane];  // 2-granule lookahead
            step2(f.x, f.y, 2 * tp);
            step2(f.z, f.w, 2 * tp + 1);
        }
        // exact re-sync: kills Taylor drift (off the per-step chain)
        sgX = sigz(__builtin_fmaf(c1sx, x, c0sx));
        uX  = __builtin_fmaf(-sgX, sgX, sgX); qX = 0.5f - sgX;
        sgY = sigz(__builtin_fmaf(c1sy, y, c0sy));
        uY  = __builtin_fmaf(-sgY, sgY, sgY); qY = 0.5f - sgY;

        if (c + 1 < NC) {
            fence_vm0();                                  // chunk c+1 DMA complete
            float4* ln = ibuf + (((c + 1) & 1) << 9);
            f0 = ln[lane];
            f1 = ln[64 + lane];
        }
        // flush chunk c: 64 rows x 16 steps x (x,y), 128 B coalesced runs
#pragma unroll
        for (int j = 0; j < 16; ++j) {
            int ro  = 4 * j + (lane >> 4);
            int col = lane & 15;
            float2 v = *(const float2*)&st[ro * STP + 2 * col];
            out2[(size_t)(R0 + ro) * TLEN + (size_t)c * K + col] = v;
        }
        if (c + 2 < NC) kick(c + 2);                      // reuse just-consumed buffer
    }
}

// ---------------------------------------------------------------------------
// Exact fallback (round-1 proven path) for general params. Grid 128x64 =
// 8192 lanes, 2 per row — unchanged from the verified round-0 kernel.
// ---------------------------------------------------------------------------
struct LaneConst {
    float c1_in, c0_in, c1_sf, c0_sf, c1_ot, c0_ot;
    float gS_in, gS_cr, gS_sf, gP_in, gP_cr, gP_sf;
};

template<bool SHARED>
__device__ __forceinline__ float do_step_exact(float s, float pre_in, const LaneConst& k) {
    float sig_in = sigz(__builtin_fmaf(k.c1_in, pre_in, k.c0_in));
    float sig_sf = sigz(__builtin_fmaf(k.c1_sf, s, k.c0_sf));
    float sig_ot;
    if (SHARED) sig_ot = sig_sf;
    else        sig_ot = sigz(__builtin_fmaf(k.c1_ot, s, k.c0_ot));
    float sig_cr = lane_swap1(sig_ot);
    float S = __builtin_fmaf(k.gS_in, sig_in, __builtin_fmaf(k.gS_cr, sig_cr, k.gS_sf * sig_sf));
    float P = __builtin_fmaf(k.gP_in, sig_in, __builtin_fmaf(k.gP_cr, sig_cr, k.gP_sf * sig_sf));
    return s + __builtin_fmaf(S, -s, P);
}

template<bool SHARED>
__device__ void run_exact(const float* __restrict__ inp, const float* __restrict__ prm,
                          float* __restrict__ out) {
    const int tid = blockIdx.x * 64 + threadIdx.x;
    const int row = tid >> 1;
    const int par = tid & 1;
    const float L2E = 1.4426950408889634f;
    const int inB = par ? 6 : 2, sfB = par ? 22 : 18, otB = par ? 14 : 10, crB = par ? 10 : 14;
    const float invc = 1.0f / prm[par];
    LaneConst k;
    float sd = prm[inB + 2], mn = prm[inB + 1];
    k.c1_in = -sd * L2E; k.c0_in = sd * mn * L2E;
    sd = prm[sfB + 2]; mn = prm[sfB + 1];
    k.c1_sf = -sd * L2E; k.c0_sf = sd * mn * L2E;
    sd = prm[otB + 2]; mn = prm[otB + 1];
    k.c1_ot = -sd * L2E; k.c0_ot = sd * mn * L2E;
    k.gS_in = prm[inB] * invc; k.gP_in = k.gS_in * prm[inB + 3];
    k.gS_sf = prm[sfB] * invc; k.gP_sf = k.gS_sf * prm[sfB + 3];
    k.gS_cr = prm[crB] * invc; k.gP_cr = k.gS_cr * prm[crB + 3];

    const float4* __restrict__ src = (const float4*)inp + (size_t)row * (TLEN / 2);
    float* __restrict__ dst = out + (size_t)row * (TLEN * 2) + par;
    float s = par ? 1.0f : 0.0f;

    float4 cur[UN], nxt[UN];
#pragma unroll
    for (int j = 0; j < UN; ++j) cur[j] = src[j];
    const int NIT = TLEN / (2 * UN);
    for (int it = 0; it < NIT; ++it) {
        if (it + 1 < NIT) {
#pragma unroll
            for (int j = 0; j < UN; ++j) nxt[j] = src[(it + 1) * UN + j];
        }
        float* dptr = dst + it * (UN * 4);
#pragma unroll
        for (int j = 0; j < UN; ++j) {
            float4 f = cur[j];
            s = do_step_exact<SHARED>(s, par ? f.y : f.x, k);
            dptr[j * 4] = s;
            s = do_step_exact<SHARED>(s, par ? f.w : f.z, k);
            dptr[j * 4 + 2] = s;
        }
#pragma unroll
        for (int j = 0; j < UN; ++j) cur[j] = nxt[j];
    }
}

__global__ __launch_bounds__(64, 1)
void memcell_scan(const float* __restrict__ inp, const float* __restrict__ prm,
                  float* __restrict__ out) {
    __shared__ float4 ibuf[2 * (K / 2) * 64];   // 16 KB input DMA double-buffer
    __shared__ float  st[RPW * STP];            // 8.7 KB output staging

    // Device-uniform guard for the fast path (unchanged from the verified kernel):
    //  - shared (mean,std) between self & cross state dirs (xx==xy, yy==yx)
    //  - g >= 0, caps > 0       -> states stay in hull{s0, pots}
    //  - sum(g/cap) <= 0.25     -> no overshoot
    //  - |dz| = std*|ds| <= 0.05 -> deg-2 sigma-Taylor (+ per-chunk exact resync)
    //  - |z| <= 20              -> sigz well-conditioned
    const bool shared = (prm[11] == prm[19]) && (prm[12] == prm[20]) &&
                        (prm[15] == prm[23]) && (prm[16] == prm[24]);
    const float capx = prm[0], capy = prm[1];
    const bool gpos = prm[2] >= 0.f && prm[6] >= 0.f && prm[10] >= 0.f &&
                      prm[14] >= 0.f && prm[18] >= 0.f && prm[22] >= 0.f &&
                      capx > 0.f && capy > 0.f;
    const float sx = (prm[2] + prm[14] + prm[18]) / capx;
    const float sy = (prm[6] + prm[10] + prm[22]) / capy;
    const float lox = fminf(0.f, fminf(prm[5], fminf(prm[17], prm[21])));
    const float hix = fmaxf(0.f, fmaxf(prm[5], fmaxf(prm[17], prm[21])));
    const float loy = fminf(1.f, fminf(prm[9], fminf(prm[13], prm[25])));
    const float hiy = fmaxf(1.f, fmaxf(prm[9], fmaxf(prm[13], prm[25])));
    const float wbx = prm[20] * sx * (hix - lox), wby = prm[24] * sy * (hiy - loy);
    const float zmx = prm[20] * fmaxf(fabsf(lox - prm[19]), fabsf(hix - prm[19]));
    const float zmy = prm[24] * fmaxf(fabsf(loy - prm[23]), fabsf(hiy - prm[23]));
    const bool fast = shared && gpos && sx <= 0.25f && sy <= 0.25f &&
                      wbx <= 0.05f && wby <= 0.05f && zmx <= 20.f && zmy <= 20.f;
    if (fast) {
        if (blockIdx.x < NROWS / RPW)           // 64 fast blocks; rest idle
            run_fast(inp, prm, out, ibuf, st);
    } else {
        if (shared) run_exact<true >(inp, prm, out);
        else        run_exact<false>(inp, prm, out);
    }
}

extern "C" void kernel_launch(void* const* d_in, const int* in_sizes, int n_in,
                              void* d_out, int out_size, void* d_ws, size_t ws_size,
                              hipStream_t stream) {
    (void)in_sizes; (void)n_in; (void)d_ws; (void)ws_size; (void)out_size;
    const float* inp = (const float*)d_in[0];
    const float* prm = (const float*)d_in[1];
    float* out = (float*)d_out;
    memcell_scan<<<dim3(128), dim3(64), 0, stream>>>(inp, prm, out);
}

// Round 3
// 351.309 us; speedup vs baseline: 1.8468x; 1.6246x over previous
//
#include <hip/hip_runtime.h>

#define TLEN  4096
#define NROWS 4096
#define RPB   32            // rows per block (owned by the scan wave)
#define K     32            // timesteps per chunk
#define NC    (TLEN / K)    // 128 chunks
#define LDPAD 66            // staged-output row pitch (dwords): 64 data + 2 pad
#define SGSL  (16 * 32)     // sgin slot: 16 tp-granules x 32 rows (float4 units)
#define STSL  (RPB * LDPAD) // output-staging slot (floats)
#define UN    8             // exact-path unroll

__device__ __forceinline__ float fexp2(float x) { return __builtin_amdgcn_exp2f(x); }
__device__ __forceinline__ float frcp(float x)  { return __builtin_amdgcn_rcpf(x); }
__device__ __forceinline__ float sigz(float z)  { return frcp(1.0f + fexp2(z)); }

// Swap adjacent lanes (lane ^ 1): DPP quad_perm [1,0,3,2].
__device__ __forceinline__ float lane_swap1(float v) {
    int r = __builtin_amdgcn_update_dpp(0, __float_as_int(v), 0xB1, 0xF, 0xF, true);
    return __int_as_float(r);
}

// ---------------------------------------------------------------------------
// Round-3 structure. Measured law (r0/r1/r2): wall = stream-length x ~6.9 cyc,
// invariant to ILP and same-SIMD co-residency. So: strip all non-serial work
// from the scan wave's stream and move it to a helper wave on another SIMD.
//
//   wave 0 (scan):   the serial recurrence only. Per step: 3 fma (affine in x),
//                    1 mul, 1 fma, 1 DPP, 1 fma, 1 add, 1 ds_write + deg-2
//                    sigma-Taylor (6) = 15 instrs. Math BIT-IDENTICAL to the
//                    verified 224us kernel (same ops, same order, same resync).
//   wave 1 (helper): input sigmoids for chunk c+1 -> LDS double-buffer
//                    (~160 instrs/chunk) and coalesced flush of chunk c-1
//                    (~64 instrs/chunk). Rides in the scan's ~3200cyc shadow.
//
// Pipeline (slot parity, barrier per chunk):
//   iteration c: scan consumes sgbuf[c&1], writes st[c&1];
//                helper produces sgbuf[(c+1)&1], flushes st[(c-1)&1].
//   __syncthreads() separates every hand-off; same-CU LDS => no cross-XCD
//   coherence machinery, no flags, no workspace.
// ---------------------------------------------------------------------------
__device__ void run_fast(const float* __restrict__ inp, const float* __restrict__ prm,
                         float* __restrict__ out,
                         float4* __restrict__ sgbuf,  // [2][16 tp][32 row] float4
                         float*  __restrict__ st) {   // [2][RPB][LDPAD]
    const int tid  = threadIdx.x;
    const int wid  = tid >> 6;          // 0 = scan wave, 1 = helper wave
    const int lane = tid & 63;
    const int R0   = blockIdx.x * RPB;
    const float L2E = 1.4426950408889634f;
    float2* __restrict__ out2 = (float2*)out;

    if (wid == 1) {
        // ---------------- helper wave ----------------
        const int r = lane & 31, h = lane >> 5;
        // input-sigmoid constants: 'ax' dir for x (base 2), 'by' dir for y (base 6)
        const float c1x = -prm[4] * L2E, c0x = prm[4] * prm[3] * L2E;
        const float c1y = -prm[8] * L2E, c0y = prm[8] * prm[7] * L2E;
        const float4* __restrict__ src = (const float4*)inp + (size_t)(R0 + r) * (TLEN / 2);

        auto produce = [&](int c) {   // sigmoids of chunk c -> sgbuf slot c&1
            float4* sl = sgbuf + ((c & 1) ? SGSL : 0);
            const int base = c * 16 + h * 8;
#pragma unroll
            for (int j = 0; j < 8; ++j) {
                float4 v = src[base + j];   // (a_t, b_t, a_t+1, b_t+1)
                float4 o;
                o.x = sigz(__builtin_fmaf(c1x, v.x, c0x));
                o.y = sigz(__builtin_fmaf(c1y, v.y, c0y));
                o.z = sigz(__builtin_fmaf(c1x, v.z, c0x));
                o.w = sigz(__builtin_fmaf(c1y, v.w, c0y));
                sl[(h * 8 + j) * 32 + r] = o;   // same layout scan's ds_read expects
            }
        };
        auto flush = [&](int c) {     // st slot c&1 -> out, 256B coalesced runs
            const float* sl = st + ((c & 1) ? STSL : 0);
            const int col = lane & 31;
#pragma unroll
            for (int j = 0; j < 16; ++j) {
                int ro = 2 * j + (lane >> 5);
                float2 v = *(const float2*)&sl[ro * LDPAD + col * 2];
                out2[(size_t)(R0 + ro) * TLEN + (size_t)c * K + col] = v;
            }
        };

        produce(0);
        __syncthreads();                       // slot 0 ready for scan
        for (int c = 0; c < NC; ++c) {
            if (c + 1 < NC) produce(c + 1);    // next chunk's sigmoids
            if (c >= 1)     flush(c - 1);      // previous chunk's outputs
            __syncthreads();
        }
        flush(NC - 1);                         // epilogue: last chunk's outputs
    } else {
        // ---------------- scan wave ----------------
        // Lane pair (2r, 2r+1) owns row r: even lane = x, odd = y (round-0 layout).
        const int r_  = lane >> 1;
        const int par = lane & 1;
        const int inB = par ? 6 : 2, sfB = par ? 22 : 18, t2B = par ? 10 : 14;
        const float ic  = 1.0f / prm[par];
        const float g1  = prm[sfB] * ic, P1 = g1 * prm[sfB + 3], Gn1 = -g1; // self
        const float g2  = prm[t2B] * ic, P2 = g2 * prm[t2B + 3], Gn2 = -g2; // cross
        const float gA  = prm[inB] * ic, PA = gA * prm[inB + 3], GnA = -gA; // input
        const float sdz = prm[sfB + 2];
        const float c1s = -sdz * L2E, c0s = sdz * prm[sfB + 1] * L2E;

        float x   = par ? 1.0f : 0.0f;
        float sig = sigz(__builtin_fmaf(c1s, x, c0s));
        float u   = __builtin_fmaf(-sig, sig, sig);   // sig*(1-sig)
        float q   = 0.5f - sig;

        auto step = [&](float sg, float* wp, int t) {
            float Av  = __builtin_fmaf(GnA, x, PA);
            float t1v = __builtin_fmaf(Gn1, x, P1);
            float t2v = __builtin_fmaf(Gn2, x, P2);
            float m   = sg * Av;                      // sgin precomputed by helper
            float b2  = __builtin_fmaf(sig, t1v, m);
            float sc  = lane_swap1(sig);              // partner's sigma
            float dx  = __builtin_fmaf(sc, t2v, b2);
            x = x + dx;
            wp[2 * t] = x;                            // ds_write_b32, imm offset
            float dz = sdz * dx;
            float tt = __builtin_fmaf(q, dz, 1.0f);
            float aa = dz * tt;
            sig = __builtin_fmaf(u, aa, sig);         // deg-2 Taylor step
            u   = __builtin_fmaf(-sig, sig, sig);
            q   = 0.5f - sig;
        };

        __syncthreads();                       // sgbuf slot 0 ready
        for (int c = 0; c < NC; ++c) {
            const float4* lb = sgbuf + ((c & 1) ? SGSL : 0);
            float* wp = st + ((c & 1) ? STSL : 0) + r_ * LDPAD + par;
            float4 f0 = lb[r_];
            float4 f1 = lb[32 + r_];
#pragma unroll
            for (int tp = 0; tp < 16; ++tp) {
                float4 f = f0; f0 = f1;
                if (tp < 14) f1 = lb[(tp + 2) * 32 + r_];   // 2-pair lookahead
                step(par ? f.y : f.x, wp, 2 * tp);
                step(par ? f.w : f.z, wp, 2 * tp + 1);
            }
            // exact re-sync: kills Taylor drift (identical to verified kernel)
            sig = sigz(__builtin_fmaf(c1s, x, c0s));
            u   = __builtin_fmaf(-sig, sig, sig);
            q   = 0.5f - sig;
            __syncthreads();                   // hand slots to helper / get next
        }
    }
}

// ---------------------------------------------------------------------------
// Exact fallback for general params (proven path; now 128-thr blocks:
// blocks 0..63 cover all 8192 lanes, rest idle).
// ---------------------------------------------------------------------------
struct LaneConst {
    float c1_in, c0_in, c1_sf, c0_sf, c1_ot, c0_ot;
    float gS_in, gS_cr, gS_sf, gP_in, gP_cr, gP_sf;
};

template<bool SHARED>
__device__ __forceinline__ float do_step_exact(float s, float pre_in, const LaneConst& k) {
    float sig_in = sigz(__builtin_fmaf(k.c1_in, pre_in, k.c0_in));
    float sig_sf = sigz(__builtin_fmaf(k.c1_sf, s, k.c0_sf));
    float sig_ot;
    if (SHARED) sig_ot = sig_sf;
    else        sig_ot = sigz(__builtin_fmaf(k.c1_ot, s, k.c0_ot));
    float sig_cr = lane_swap1(sig_ot);
    float S = __builtin_fmaf(k.gS_in, sig_in, __builtin_fmaf(k.gS_cr, sig_cr, k.gS_sf * sig_sf));
    float P = __builtin_fmaf(k.gP_in, sig_in, __builtin_fmaf(k.gP_cr, sig_cr, k.gP_sf * sig_sf));
    return s + __builtin_fmaf(S, -s, P);
}

template<bool SHARED>
__device__ void run_exact(const float* __restrict__ inp, const float* __restrict__ prm,
                          float* __restrict__ out) {
    const int tid = blockIdx.x * 128 + threadIdx.x;
    const int row = tid >> 1;
    if (row >= NROWS) return;
    const int par = tid & 1;
    const float L2E = 1.4426950408889634f;
    const int inB = par ? 6 : 2, sfB = par ? 22 : 18, otB = par ? 14 : 10, crB = par ? 10 : 14;
    const float invc = 1.0f / prm[par];
    LaneConst k;
    float sd = prm[inB + 2], mn = prm[inB + 1];
    k.c1_in = -sd * L2E; k.c0_in = sd * mn * L2E;
    sd = prm[sfB + 2]; mn = prm[sfB + 1];
    k.c1_sf = -sd * L2E; k.c0_sf = sd * mn * L2E;
    sd = prm[otB + 2]; mn = prm[otB + 1];
    k.c1_ot = -sd * L2E; k.c0_ot = sd * mn * L2E;
    k.gS_in = prm[inB] * invc; k.gP_in = k.gS_in * prm[inB + 3];
    k.gS_sf = prm[sfB] * invc; k.gP_sf = k.gS_sf * prm[sfB + 3];
    k.gS_cr = prm[crB] * invc; k.gP_cr = k.gS_cr * prm[crB + 3];

    const float4* __restrict__ src = (const float4*)inp + (size_t)row * (TLEN / 2);
    float* __restrict__ dst = out + (size_t)row * (TLEN * 2) + par;
    float s = par ? 1.0f : 0.0f;

    float4 cur[UN], nxt[UN];
#pragma unroll
    for (int j = 0; j < UN; ++j) cur[j] = src[j];
    const int NIT = TLEN / (2 * UN);
    for (int it = 0; it < NIT; ++it) {
        if (it + 1 < NIT) {
#pragma unroll
            for (int j = 0; j < UN; ++j) nxt[j] = src[(it + 1) * UN + j];
        }
        float* dptr = dst + it * (UN * 4);
#pragma unroll
        for (int j = 0; j < UN; ++j) {
            float4 f = cur[j];
            s = do_step_exact<SHARED>(s, par ? f.y : f.x, k);
            dptr[j * 4] = s;
            s = do_step_exact<SHARED>(s, par ? f.w : f.z, k);
            dptr[j * 4 + 2] = s;
        }
#pragma unroll
        for (int j = 0; j < UN; ++j) cur[j] = nxt[j];
    }
}

__global__ __launch_bounds__(128, 1)
void memcell_scan(const float* __restrict__ inp, const float* __restrict__ prm,
                  float* __restrict__ out) {
    __shared__ float4 sgbuf[2 * SGSL];   // 16 KB sgin double-buffer
    __shared__ float  st[2 * STSL];      // 16.9 KB output staging double-buffer

    // Device-uniform guard for the fast path (unchanged from the verified kernel):
    //  - shared (mean,std) between self & cross state dirs (xx==xy, yy==yx)
    //  - g >= 0, caps > 0       -> states stay in hull{s0, pots}
    //  - sum(g/cap) <= 0.25     -> no overshoot
    //  - |dz| = std*|ds| <= 0.05 -> deg-2 sigma-Taylor (+ per-chunk exact resync)
    //  - |z| <= 20              -> sigz well-conditioned
    const bool shared = (prm[11] == prm[19]) && (prm[12] == prm[20]) &&
                        (prm[15] == prm[23]) && (prm[16] == prm[24]);
    const float capx = prm[0], capy = prm[1];
    const bool gpos = prm[2] >= 0.f && prm[6] >= 0.f && prm[10] >= 0.f &&
                      prm[14] >= 0.f && prm[18] >= 0.f && prm[22] >= 0.f &&
                      capx > 0.f && capy > 0.f;
    const float sx = (prm[2] + prm[14] + prm[18]) / capx;
    const float sy = (prm[6] + prm[10] + prm[22]) / capy;
    const float lox = fminf(0.f, fminf(prm[5], fminf(prm[17], prm[21])));
    const float hix = fmaxf(0.f, fmaxf(prm[5], fmaxf(prm[17], prm[21])));
    const float loy = fminf(1.f, fminf(prm[9], fminf(prm[13], prm[25])));
    const float hiy = fmaxf(1.f, fmaxf(prm[9], fmaxf(prm[13], prm[25])));
    const float wbx = prm[20] * sx * (hix - lox), wby = prm[24] * sy * (hiy - loy);
    const float zmx = prm[20] * fmaxf(fabsf(lox - prm[19]), fabsf(hix - prm[19]));
    const float zmy = prm[24] * fmaxf(fabsf(loy - prm[23]), fabsf(hiy - prm[23]));
    const bool fast = shared && gpos && sx <= 0.25f && sy <= 0.25f &&
                      wbx <= 0.05f && wby <= 0.05f && zmx <= 20.f && zmy <= 20.f;
    if (fast) {
        run_fast(inp, prm, out, sgbuf, st);
    } else {
        if (shared) run_exact<true >(inp, prm, out);
        else        run_exact<false>(inp, prm, out);
    }
}

extern "C" void kernel_launch(void* const* d_in, const int* in_sizes, int n_in,
                              void* d_out, int out_size, void* d_ws, size_t ws_size,
                              hipStream_t stream) {
    (void)in_sizes; (void)n_in; (void)d_ws; (void)ws_size; (void)out_size;
    const float* inp = (const float*)d_in[0];
    const float* prm = (const float*)d_in[1];
    float* out = (float*)d_out;
    memcell_scan<<<dim3(NROWS / RPB), dim3(128), 0, stream>>>(inp, prm, out);
}